// Round 17
// baseline (137.731 us; speedup 1.0000x reference)
//
#include <hip/hip_runtime.h>
#include <hip/hip_bf16.h>
#include <math.h>

#define TPB 256
#define XS    132           // f32 X region el-stride (dwords); x -> att scratch
#define OFF_X  0
#define OFF_XR 4224         // [32][17] uint4: xr; later attW [8i][8np][32b^swz] u32
#define XRU4   1056         // OFF_XR/4 : uint4 index of XR region
#define SMEM_FLOATS (4224 + 2176)       // 6400 dwords = 25600 B
#define SMEM_BYTES  (SMEM_FLOATS * 4)

// ---- Cl(3,0): slot s (0..43) of the GP pair-sum (verified) ----
// extended: slots 44..51 = left-linear slot for blade j=S-44 (product = x[b,n,j], weight = w_left)
// slot 52 = zero pad.
constexpr int SCNT[44] = {1,1,1,1,1,1,1,1, 3,1,1,1, 2,2,2,2,2,2, 1,1,1, 3,
                          3, 2,2,2, 1,1,1,1,1,1, 2,2,2, 3, 1,1,1,1,1,1,1,1};
constexpr int T1I[44] = {0,0,0,0,0,0,0,0, 1,1,2,3, 2,1,1,1,1,2, 3,2,1, 1,
                         4, 4,4,5, 6,5,4,4,5,6, 5,4,4, 4, 7,7,7,7,7,7,7,7};
constexpr int T1K[44] = {0,1,2,3,4,5,6,7, 1,0,0,0, 4,4,5,2,3,3, 7,7,7, 6,
                         4, 2,1,1, 7,7,7,0,0,0, 6,6,5, 3, 7,6,5,4,3,2,1,0};
constexpr int T1S[44] = {1,1,1,1,1,1,1,1, 1,1,1,1, 0,1,1,1,1,1, 1,0,1, 1,
                         0, 1,0,0, 0,1,0,1,1,1, 0,1,0, 1, 0,0,1,0,1,0,1,1};
constexpr int T2I[44] = {0,0,0,0,0,0,0,0, 2,0,0,0, 3,3,2,2,3,3, 0,0,0, 2,
                         5, 5,6,6, 0,0,0,0,0,0, 6,6,5, 5, 0,0,0,0,0,0,0,0};
constexpr int T2K[44] = {0,0,0,0,0,0,0,0, 2,0,0,0, 5,6,6,1,1,2, 0,0,0, 5,
                         5, 3,3,2, 0,0,0,0,0,0, 5,4,4, 2, 0,0,0,0,0,0,0,0};
constexpr int T2S[44] = {1,1,1,1,1,1,1,1, 1,1,1,1, 0,0,1,0,0,0, 1,1,1, 0,
                         0, 1,1,0, 1,1,1,1,1,1, 1,0,1, 0, 1,1,1,1,1,1,1,1};
constexpr int T3I[44] = {0,0,0,0,0,0,0,0, 3,0,0,0, 0,0,0,0,0,0, 0,0,0, 3,
                         6, 0,0,0, 0,0,0,0,0,0, 0,0,0, 6, 0,0,0,0,0,0,0,0};
constexpr int T3K[44] = {0,0,0,0,0,0,0,0, 3,0,0,0, 0,0,0,0,0,0, 0,0,0, 4,
                         6, 0,0,0, 0,0,0,0,0,0, 0,0,0, 1, 0,0,0,0,0,0,0,0};
constexpr int T3S[44] = {1,1,1,1,1,1,1,1, 1,1,1,1, 1,1,1,1,1,1, 1,1,1, 1,
                         0, 1,1,1, 1,1,1,1,1,1, 1,1,1, 1, 1,1,1,1,1,1,1,1};
constexpr int CP[44] = {
    0, 1,1,1, 2,2,2, 3,
    4, 5,5,5, 6,6,6, 7,7,7, 8,8,8, 9,
    10, 11,11,11, 12,12,12, 13,13,13, 14,14,14, 15,
    16, 17,17,17, 18,18,18, 19};
// slot-PAIRS incl. lf slots: k = 2n + slot. Q = jh*15 + p. Both slots of a pair share blade j.
constexpr int PPS2[30][2] = {
    {0,8},{22,36},{44,52}, {1,9},{12,23},{26,37},{45,52}, {2,10},{13,24},{27,38},{46,52},
    {3,11},{14,25},{28,39},{47,52},
    {4,15},{18,29},{32,40},{48,52}, {5,16},{19,30},{33,41},{49,52}, {6,17},{20,31},{34,42},{50,52},
    {7,21},{35,43},{51,52}};
constexpr int FRS2[30] = {0,0,0, 1,1,1,1, 2,2,2,2, 3,3,3,3,  0,0,0,0, 1,1,1,1, 2,2,2,2, 3,3,3};

typedef __attribute__((ext_vector_type(8))) short bf16x8;
typedef __attribute__((ext_vector_type(4))) float f32x4;
union U4B { uint4 u; bf16x8 h; };

__device__ __forceinline__ float sigmoidf_(float v) {
    return __builtin_amdgcn_rcpf(1.0f + __expf(-v));
}
__device__ __forceinline__ unsigned pk2(float lo, float hi) {
    __hip_bfloat162 h = __float22bfloat162_rn(make_float2(lo, hi));
    return *reinterpret_cast<unsigned*>(&h);
}
__device__ __forceinline__ void unpkrow(uint4 u, float* v) {
    v[0]=__uint_as_float(u.x<<16); v[1]=__uint_as_float(u.x&0xffff0000u);
    v[2]=__uint_as_float(u.y<<16); v[3]=__uint_as_float(u.y&0xffff0000u);
    v[4]=__uint_as_float(u.z<<16); v[5]=__uint_as_float(u.z&0xffff0000u);
    v[6]=__uint_as_float(u.w<<16); v[7]=__uint_as_float(u.w&0xffff0000u);
}

// tz for slot S (compile-time): S<44 = GP pair-sum; 44..51 = lf (product is x itself); 52 = zero
template<int S>
__device__ __forceinline__ float tz_slot(const float* xf, const float* xr) {
    if constexpr (S >= 52) {
        return 0.0f;
    } else if constexpr (S >= 44) {
        return xf[S - 44];
    } else {
        float v = xf[T1I[S]] * xr[T1K[S]];
        if constexpr (!T1S[S]) v = -v;
        if constexpr (SCNT[S] > 1) {
            if constexpr (T2S[S]) v = fmaf( xf[T2I[S]], xr[T2K[S]], v);
            else                  v = fmaf(-xf[T2I[S]], xr[T2K[S]], v);
        }
        if constexpr (SCNT[S] > 2) {
            if constexpr (T3S[S]) v = fmaf( xf[T3I[S]], xr[T3K[S]], v);
            else                  v = fmaf(-xf[T3I[S]], xr[T3K[S]], v);
        }
        return v;
    }
}

// half-MFMA pass: HALF=0 fills A dwords x,y (n=4lh+0,1), HALF=1 fills z,w (n=4lh+2,3).
// Zero dwords contribute exactly 0 to the K-sum; cf accumulates across both passes.
template<int JH, int P, int HALF>
__device__ __forceinline__ void gp_half(const float (&xf)[2][8], const float (&xrf)[2][8],
                                        const uint4* __restrict__ wsg, int lane,
                                        f32x4 (&cf)[4]) {
    if constexpr (P < 15) {
        constexpr int Q  = JH*15 + P;
        constexpr int S0 = PPS2[Q][0], S1 = PPS2[Q][1], F = FRS2[Q];
        const unsigned d0 = pk2(tz_slot<S0>(xf[0], xrf[0]), tz_slot<S1>(xf[0], xrf[0]));
        const unsigned d1 = pk2(tz_slot<S0>(xf[1], xrf[1]), tz_slot<S1>(xf[1], xrf[1]));
        U4B a;
        if constexpr (HALF == 0) { a.u = make_uint4(d0, d1, 0u, 0u); }
        else                     { a.u = make_uint4(0u, 0u, d0, d1); }
        U4B wb; wb.u = wsg[Q*64 + lane];
        cf[F] = __builtin_amdgcn_mfma_f32_16x16x32_bf16(a.h, wb.h, cf[F], 0, 0, 0);
        gp_half<JH, P+1, HALF>(xf, xrf, wsg, lane, cf);
    }
}

// ---- prep: pack w_up (A-frags under pi), w_down (K=32 B-frags), w_gp+w_left (C B-frags),
//            w_right (A-frags for the xr-GEMM) ----
// sigma (verified): lane l -> row/col = l&15, k-slots ks0 = 8*(l>>4)+2*jp (+1)
// pi(mt,lh,r) = 32*(mt>>1) + 4*(mt&1) + 8*lh + r   (m2 relabeling; see kernel phase D)
__global__ void prep_pack(const float* __restrict__ w_up,
                          const float* __restrict__ w_down,
                          const float* __restrict__ w_gp,
                          const float* __restrict__ w_left,
                          const float* __restrict__ w_right,
                          unsigned* __restrict__ wsu,
                          unsigned* __restrict__ wsd,
                          uint4* __restrict__ wsg,
                          uint4* __restrict__ wsr)
{
    const int t = blockIdx.x * 256 + threadIdx.x;       // 0..14847
    if (t < 8192) {
        // wsu: up A-frags. frag f = mt*8 + i. lane row rho = l&15 -> m2 = pi(mt, rho>>2, rho&3)
        const int d  = t;
        const int f  = d >> 8;
        const int rj = d & 255;
        const int l  = rj >> 2, jp = rj & 3;
        const int mt = f >> 3, i = f & 7;
        const int g  = (i == 0) ? 0 : (i <= 3 ? 1 : (i <= 6 ? 2 : 3));
        const int rho = l & 15;
        const int m2 = 32*(mt>>1) + 4*(mt&1) + 8*(rho>>2) + (rho&3);
        const int n0 = ((l >> 4) << 3) + (jp << 1);
        const float v0 = (n0     < 16) ? w_up[(m2*16 + n0    )*4 + g] : 0.f;
        const float v1 = (n0 + 1 < 16) ? w_up[(m2*16 + n0 + 1)*4 + g] : 0.f;
        wsu[d] = pk2(v0, v1);
    } else if (t < 12288) {
        // wsd: down B-frags, K=32. frag f = kt*8 + i. col m = l&15, k = m2 = 32kt + ks
        const int d  = t - 8192;
        const int f  = d >> 8;
        const int rj = d & 255;
        const int l  = rj >> 2, jp = rj & 3;
        const int kt = f >> 3, i = f & 7;
        const int g  = (i == 0) ? 0 : (i <= 3 ? 1 : (i <= 6 ? 2 : 3));
        const int m  = l & 15;
        const int k0 = 32*kt + ((l >> 4) << 3) + (jp << 1);
        wsd[d] = pk2(w_down[(m*64 + k0    )*4 + g],
                     w_down[(m*64 + k0 + 1)*4 + g]);
    } else if (t < 14208) {
        const int u = t - 12288;                        // 0..1919
        const int l = u & 63, q = u >> 6;               // q 0..29
        const int m = l & 15, lh = l >> 4;
        const int s0 = PPS2[q][0], s1 = PPS2[q][1];
        auto wslot = [&](int S, int n) -> float {
            if (S >= 52) return 0.f;
            if (S >= 44) {
                const int j = S - 44;
                const int gg = (j == 0) ? 0 : (j <= 3 ? 1 : (j <= 6 ? 2 : 3));
                return w_left[(m*16 + n)*4 + gg];
            }
            return w_gp[(m*16 + n)*20 + CP[S]];
        };
        uint4 val;
        { const int n = 4*lh + 0; val.x = pk2(wslot(s0, n), wslot(s1, n)); }
        { const int n = 4*lh + 1; val.y = pk2(wslot(s0, n), wslot(s1, n)); }
        { const int n = 4*lh + 2; val.z = pk2(wslot(s0, n), wslot(s1, n)); }
        { const int n = 4*lh + 3; val.w = pk2(wslot(s0, n), wslot(s1, n)); }
        wsg[q*64 + l] = val;
    } else if (t < 14720) {
        // wsr: xr-GEMM A-frags, one per blade j. row nch = l&15 (output channel),
        // k = input channel (k>=16 -> 0). A[nch][k] = w_right[nch][k][g(j)].
        const int u2 = t - 14208;                       // 0..511
        const int l = u2 & 63, j = u2 >> 6;             // j 0..7
        const int g  = (j == 0) ? 0 : (j <= 3 ? 1 : (j <= 6 ? 2 : 3));
        const int nch = l & 15;
        const int lh2 = l >> 4;
        uint4 val = make_uint4(0u,0u,0u,0u);
        if (lh2 < 2) {
            const int kb = 8*lh2;
            val.x = pk2(w_right[(nch*16+kb+0)*4+g], w_right[(nch*16+kb+1)*4+g]);
            val.y = pk2(w_right[(nch*16+kb+2)*4+g], w_right[(nch*16+kb+3)*4+g]);
            val.z = pk2(w_right[(nch*16+kb+4)*4+g], w_right[(nch*16+kb+5)*4+g]);
            val.w = pk2(w_right[(nch*16+kb+6)*4+g], w_right[(nch*16+kb+7)*4+g]);
        }
        wsr[j*64 + l] = val;
    }
}

__global__ __launch_bounds__(TPB, 4)
void mv_block_kernel(const float* __restrict__ xg,
                     const float* __restrict__ a_norm,
                     const float* __restrict__ b_left,
                     const float* __restrict__ b_up,
                     const float* __restrict__ a_act,
                     const float* __restrict__ b_act,
                     const float* __restrict__ b_down,
                     const uint4* __restrict__ wsu,
                     const uint4* __restrict__ wsd,
                     const uint4* __restrict__ wsg,
                     const uint4* __restrict__ wsr,
                     float* __restrict__ outg)
{
    extern __shared__ float sm[];
    uint4* uXR = ((uint4*)sm) + XRU4;
    const int t = threadIdx.x;
    const int b = t & 63;                                   // lane
    const int w = __builtin_amdgcn_readfirstlane(t >> 6);   // wave 0..3 (uniform)
    const int g = blockIdx.x;
    const int Mtb  = (w & 1) << 4;                          // M-tile base (16 of 32 batch rows)
    const int jh   = w >> 1;                                // blade-half 0/1
    const int lcol = b & 15;
    const int lh   = b >> 4;

    // ---------- stage x (coalesced, f32): 32 batch rows. NO barrier here: phase A' reads x
    //            directly from GLOBAL (identical bits), so staging completion is only needed
    //            by phase C -- covered by the single barrier after A'.
    {
        const float4* xs = (const float4*)xg + (size_t)g * 1024;
        #pragma unroll
        for (int r = 0; r < 4; ++r) {
            const int idx = r * TPB + t;
            const float4 v = xs[idx];
            const int el = idx >> 5, off = idx & 31;
            *(float4*)&sm[OFF_X + el * XS + off * 4] = v;
        }
    }

    // ---------- phase A' (MFMA right-linear) + in-reg gated normalization -> uXR bf16 ----------
    // swapped GEMM per blade j (own half): xr[nch, b] = wsr(A)[nch,k] x Bf(x)[k,b].
    // x read from GLOBAL (L2/L3-served; lines co-fetched by the staging loads above).
    {
        uint4 Bf[4];
        #pragma unroll
        for (int q = 0; q < 4; ++q) Bf[q] = make_uint4(0u,0u,0u,0u);
        if (lh < 2) {                    // k-slots >=16 multiply zero A rows
            float4 xk[8];
            const float* xb = xg + (size_t)g * 4096 + (Mtb + lcol)*128 + (jh<<2);
            #pragma unroll
            for (int kk = 0; kk < 8; ++kk)
                xk[kk] = *(const float4*)&xb[(8*lh + kk)*8];
            Bf[0] = make_uint4(pk2(xk[0].x,xk[1].x), pk2(xk[2].x,xk[3].x),
                               pk2(xk[4].x,xk[5].x), pk2(xk[6].x,xk[7].x));
            Bf[1] = make_uint4(pk2(xk[0].y,xk[1].y), pk2(xk[2].y,xk[3].y),
                               pk2(xk[4].y,xk[5].y), pk2(xk[6].y,xk[7].y));
            Bf[2] = make_uint4(pk2(xk[0].z,xk[1].z), pk2(xk[2].z,xk[3].z),
                               pk2(xk[4].z,xk[5].z), pk2(xk[6].z,xk[7].z));
            Bf[3] = make_uint4(pk2(xk[0].w,xk[1].w), pk2(xk[2].w,xk[3].w),
                               pk2(xk[4].w,xk[5].w), pk2(xk[6].w,xk[7].w));
        }
        f32x4 ur[4];
        #pragma unroll
        for (int q = 0; q < 4; ++q) {
            U4B a;  a.u  = wsr[((jh<<2) + q)*64 + b];
            U4B bb; bb.u = Bf[q];
            f32x4 z; z[0]=0.f; z[1]=0.f; z[2]=0.f; z[3]=0.f;
            ur[q] = __builtin_amdgcn_mfma_f32_16x16x32_bf16(a.h, bb.h, z, 0, 0, 0);
        }
        unsigned* uw = (unsigned*)(sm + OFF_XR);
        #pragma unroll
        for (int r = 0; r < 4; ++r) {
            const int nch = 4*lh + r;
            const float4 an = *(const float4*)&a_norm[nch*4];
            float v0 = ur[0][r], v1 = ur[1][r], v2 = ur[2][r], v3 = ur[3][r];
            if (jh == 0) {                       // blades 0..3: grade0 + grade1
                const float i0 = __builtin_amdgcn_rcpf(
                    sigmoidf_(an.x)*(sqrtf(v0*v0)-1.0f)+1.0f + 1e-6f);
                const float i1 = __builtin_amdgcn_rcpf(
                    sigmoidf_(an.y)*(sqrtf(v1*v1+v2*v2+v3*v3)-1.0f)+1.0f + 1e-6f);
                v0*=i0; v1*=i1; v2*=i1; v3*=i1;
            } else {                             // blades 4..7: grade2 + grade3
                const float i2 = __builtin_amdgcn_rcpf(
                    sigmoidf_(an.z)*(sqrtf(v0*v0+v1*v1+v2*v2)-1.0f)+1.0f + 1e-6f);
                const float i3 = __builtin_amdgcn_rcpf(
                    sigmoidf_(an.w)*(sqrtf(v3*v3)-1.0f)+1.0f + 1e-6f);
                v0*=i2; v1*=i2; v2*=i2; v3*=i3;
            }
            // uXR[b][nch] uint4 = blades 0..7 bf16; this wave writes its half's 2 dwords
            const int dwb = (((Mtb + lcol)*17 + nch) << 2) + (jh << 1);
            uw[dwb]     = pk2(v0, v1);
            uw[dwb + 1] = pk2(v2, v3);
        }
    }
    __syncthreads();   // single barrier: covers stage-x stores AND uXR writes

    // ---------- phase C (MFMA): b_left + lf + gp accumulated together; att = cf/sqrt2 ----------
    // 2 half-passes (n=4lh+{0,1} then {2,3}), 15 pairs each incl. lf slots; cf[0] seeded b_left.
    {
        const int brow = Mtb + lcol;
        f32x4 cf[4];
        {
            const float bl = (jh == 0) ? b_left[lcol] : 0.0f;
            cf[0][0]=bl; cf[0][1]=bl; cf[0][2]=bl; cf[0][3]=bl;
            #pragma unroll
            for (int q = 1; q < 4; ++q) { cf[q][0]=0.f; cf[q][1]=0.f; cf[q][2]=0.f; cf[q][3]=0.f; }
        }
        float xf[2][8], xrf[2][8];
        // half 0: n = 4lh+0, 4lh+1
        #pragma unroll
        for (int jp = 0; jp < 2; ++jp) {
            const int n = 4*lh + jp;
            const float4 u0 = *(const float4*)&sm[OFF_X + brow*XS + n*8];
            const float4 u1 = *(const float4*)&sm[OFF_X + brow*XS + n*8 + 4];
            xf[jp][0]=u0.x; xf[jp][1]=u0.y; xf[jp][2]=u0.z; xf[jp][3]=u0.w;
            xf[jp][4]=u1.x; xf[jp][5]=u1.y; xf[jp][6]=u1.z; xf[jp][7]=u1.w;
            unpkrow(uXR[brow*17 + n], xrf[jp]);
        }
        if (jh == 0) gp_half<0,0,0>(xf, xrf, wsg, b, cf);
        else         gp_half<1,0,0>(xf, xrf, wsg, b, cf);
        // half 1: n = 4lh+2, 4lh+3 (reuse xf/xrf storage)
        #pragma unroll
        for (int jp = 0; jp < 2; ++jp) {
            const int n = 4*lh + 2 + jp;
            const float4 u0 = *(const float4*)&sm[OFF_X + brow*XS + n*8];
            const float4 u1 = *(const float4*)&sm[OFF_X + brow*XS + n*8 + 4];
            xf[jp][0]=u0.x; xf[jp][1]=u0.y; xf[jp][2]=u0.z; xf[jp][3]=u0.w;
            xf[jp][4]=u1.x; xf[jp][5]=u1.y; xf[jp][6]=u1.z; xf[jp][7]=u1.w;
            unpkrow(uXR[brow*17 + n], xrf[jp]);
        }
        if (jh == 0) gp_half<0,0,1>(xf, xrf, wsg, b, cf);
        else         gp_half<1,0,1>(xf, xrf, wsg, b, cf);
        __syncthreads();   // all waves done reading x (X) and xr (uXR)
        // att = cf * inv_sqrt2 -> X region f32 [b][m*8 + j]  (x is dead)
        const float s2 = 0.70710678118654752f;
        #pragma unroll
        for (int r = 0; r < 4; ++r) {
            *(float4*)&sm[OFF_X + (Mtb + 4*lh + r)*XS + (lcol<<3) + (jh<<2)] =
                make_float4(cf[0][r]*s2, cf[1][r]*s2, cf[2][r]*s2, cf[3][r]*s2);
        }
    }
    __syncthreads();

    // ---------- attW bf16 assembly from X (transient regs only) ----------
    // thread covers (np = channel pair, batch): np = 2w | (b>>5), batch = b&31
    {
        const int np = (w << 1) | (b >> 5);
        const int bt = b & 31;
        const float* gx = &sm[OFF_X + bt*XS];
        const float4 a0 = *(const float4*)&gx[np*16];
        const float4 a1 = *(const float4*)&gx[np*16 + 4];
        const float4 b0 = *(const float4*)&gx[np*16 + 8];
        const float4 b1 = *(const float4*)&gx[np*16 + 12];
        unsigned* attW = (unsigned*)(sm + OFF_XR);
        const int bsw = bt ^ ((np >> 2) << 4);
        attW[(0<<8) + (np<<5) + bsw] = pk2(a0.x, b0.x);
        attW[(1<<8) + (np<<5) + bsw] = pk2(a0.y, b0.y);
        attW[(2<<8) + (np<<5) + bsw] = pk2(a0.z, b0.z);
        attW[(3<<8) + (np<<5) + bsw] = pk2(a0.w, b0.w);
        attW[(4<<8) + (np<<5) + bsw] = pk2(a1.x, b1.x);
        attW[(5<<8) + (np<<5) + bsw] = pk2(a1.y, b1.y);
        attW[(6<<8) + (np<<5) + bsw] = pk2(a1.z, b1.z);
        attW[(7<<8) + (np<<5) + bsw] = pk2(a1.w, b1.w);
    }
    __syncthreads();

    // ---------- phase D: swapped up-GEMM (h^T in regs) -> in-reg silu -> reg-packed down-GEMM ----
    // up (per blade i): C'[m2,b] = wsu(A)[m2,n] x attB(B)[n,b]; pi relabel aligns C' rows with
    // down A k-slots. Incremental pack: mte=0 result packed to 8 dwords before mte=1 runs.
    // X region is untouched during D (att f32 parks there).
    f32x4 dC[4];
    #pragma unroll
    for (int q = 0; q < 4; ++q) { dC[q][0]=0.f; dC[q][1]=0.f; dC[q][2]=0.f; dC[q][3]=0.f; }
    {
        // B-frags (att) per blade, loaded once; k>=16 rows multiply zero A -> zeros fine
        uint4 attB[4];
        {
            const unsigned* aw = (const unsigned*)(sm + OFF_XR);
            #pragma unroll
            for (int q = 0; q < 4; ++q) {
                uint4 v = make_uint4(0u,0u,0u,0u);
                if (lh < 2) {
                    const int base = ((jh*4 + q) << 8);
                    const int bb = (Mtb + lcol) ^ (lh << 4);
                    v.x = aw[base + ((4*lh+0)<<5) + bb];
                    v.y = aw[base + ((4*lh+1)<<5) + bb];
                    v.z = aw[base + ((4*lh+2)<<5) + bb];
                    v.w = aw[base + ((4*lh+3)<<5) + bb];
                }
                attB[q] = v;
            }
        }
        #pragma unroll
        for (int kt = 0; kt < 2; ++kt) {
            unsigned pkl[4][2];                     // packed mte=0 A-dwords (8 regs)
            #pragma unroll
            for (int mte = 0; mte < 2; ++mte) {
                const int mt = 2*kt + mte;
                f32x4 uc[4];
                #pragma unroll
                for (int q = 0; q < 4; ++q) {
                    U4B a;  a.u  = wsu[((mt<<3) + jh*4 + q)*64 + b];
                    U4B bb; bb.u = attB[q];
                    f32x4 z; z[0]=0.f; z[1]=0.f; z[2]=0.f; z[3]=0.f;
                    uc[q] = __builtin_amdgcn_mfma_f32_16x16x32_bf16(a.h, bb.h, z, 0, 0, 0);
                }
                // silu in C'-layout: lane holds (b=lcol-col, m2 = m2base + r)
                const int m2base = 32*kt + 4*mte + 8*lh;
                const float4 bup4 = *(const float4*)&b_up[m2base];
                const float* bupp = &bup4.x;
                #pragma unroll
                for (int r = 0; r < 4; ++r) {
                    const float4 aa = *(const float4*)&a_act[(m2base + r)*4];
                    const float4 bc = *(const float4*)&b_act[(m2base + r)*4];
                    float h0 = uc[0][r], h1 = uc[1][r], h2 = uc[2][r], h3 = uc[3][r];
                    if (jh == 0) {                   // blades 0..3: grade0 + grade1
                        h0 += bupp[r];
                        const float g0 = sigmoidf_(fmaf(aa.x, h0, bc.x));
                        const float g1 = sigmoidf_(fmaf(aa.y, h1*h1 + h2*h2 + h3*h3, bc.y));
                        h0 *= g0; h1 *= g1; h2 *= g1; h3 *= g1;
                    } else {                         // blades 4..7: grade2 + grade3
                        const float g2 = sigmoidf_(fmaf(aa.z, h0*h0 + h1*h1 + h2*h2, bc.z));
                        const float g3 = sigmoidf_(fmaf(aa.w, h3*h3, bc.w));
                        h0 *= g2; h1 *= g2; h2 *= g2; h3 *= g3;
                    }
                    uc[0][r]=h0; uc[1][r]=h1; uc[2][r]=h2; uc[3][r]=h3;
                }
                if (mte == 0) {
                    #pragma unroll
                    for (int q = 0; q < 4; ++q) {
                        pkl[q][0] = pk2(uc[q][0], uc[q][1]);
                        pkl[q][1] = pk2(uc[q][2], uc[q][3]);
                    }
                } else {
                    // combine with mte=0 halves and run the down MFMA (K=32 full)
                    #pragma unroll
                    for (int q = 0; q < 4; ++q) {
                        U4B a;
                        a.u.x = pkl[q][0];
                        a.u.y = pkl[q][1];
                        a.u.z = pk2(uc[q][0], uc[q][1]);
                        a.u.w = pk2(uc[q][2], uc[q][3]);
                        U4B wb; wb.u = wsd[((kt<<3) + jh*4 + q)*64 + b];
                        dC[q] = __builtin_amdgcn_mfma_f32_16x16x32_bf16(a.h, wb.h, dC[q], 0, 0, 0);
                    }
                }
            }
        }
    }
    // --- out = att + dC (+ b_down on scalar blade), stored DIRECTLY to global from regs.
    //     att read from X (same addresses this thread wrote in phase C -> same-thread LDS
    //     order guarantees visibility, no barrier). No final barrier / epilogue needed.
    {
        const float bd = (jh == 0) ? b_down[lcol] : 0.0f;
        float4* og = (float4*)outg + (size_t)g * 1024;
        #pragma unroll
        for (int r = 0; r < 4; ++r) {
            const int br = Mtb + (lh<<2) + r;
            float4 av = *(const float4*)&sm[OFF_X + br*XS + (lcol<<3) + (jh<<2)];
            av.x = (av.x + dC[0][r]) + bd;
            av.y += dC[1][r];
            av.z += dC[2][r];
            av.w += dC[3][r];
            og[br*32 + (lcol<<1) + jh] = av;
        }
    }
}

extern "C" void kernel_launch(void* const* d_in, const int* in_sizes, int n_in,
                              void* d_out, int out_size, void* d_ws, size_t ws_size,
                              hipStream_t stream) {
    const float* x       = (const float*)d_in[0];
    const float* w_right = (const float*)d_in[1];
    const float* a_norm  = (const float*)d_in[2];
    const float* w_gp    = (const float*)d_in[3];
    const float* w_left  = (const float*)d_in[4];
    const float* b_left  = (const float*)d_in[5];
    const float* w_up    = (const float*)d_in[6];
    const float* b_up    = (const float*)d_in[7];
    const float* a_act   = (const float*)d_in[8];
    const float* b_act   = (const float*)d_in[9];
    const float* w_down  = (const float*)d_in[10];
    const float* b_down  = (const float*)d_in[11];
    float* out = (float*)d_out;

    const int B = in_sizes[0] / 128;        // 65536
    const int nblocks = B / 32;             // 2048 (32 batch rows per 256-thread block)

    unsigned* wsu = (unsigned*)d_ws;        // 32 KB up A-frags (pi-ordered)
    unsigned* wsd = wsu + 8192;             // 16 KB down B-frags (K=32)
    uint4*    wsg = (uint4*)(wsd + 4096);   // 30 KB C-phase B-frags (30 slot-pairs x 64 lanes)
    uint4*    wsr = wsg + 1920;             // 8 KB xr-GEMM A-frags (8 blades x 64 lanes)

    prep_pack<<<58, 256, 0, stream>>>(w_up, w_down, w_gp, w_left, w_right,
                                      wsu, wsd, wsg, wsr);

    (void)hipFuncSetAttribute((const void*)mv_block_kernel,
                              hipFuncAttributeMaxDynamicSharedMemorySize, SMEM_BYTES);
    mv_block_kernel<<<nblocks, TPB, SMEM_BYTES, stream>>>(
        x, a_norm, b_left, b_up, a_act, b_act, b_down,
        (const uint4*)wsu, (const uint4*)wsd, (const uint4*)wsg, (const uint4*)wsr, out);
}

// Round 18
// 131.799 us; speedup vs baseline: 1.0450x; 1.0450x over previous
//
#include <hip/hip_runtime.h>
#include <hip/hip_bf16.h>
#include <math.h>

#define TPB 256
#define XS    132           // f32 X region el-stride (dwords); x -> att scratch
#define OFF_X  0
#define OFF_XR 4224         // [32][17] uint4: xr; later attW [8i][8np][32b^swz] u32
#define XRU4   1056         // OFF_XR/4 : uint4 index of XR region
#define SMEM_FLOATS (4224 + 2176)       // 6400 dwords = 25600 B
#define SMEM_BYTES  (SMEM_FLOATS * 4)

// ---- Cl(3,0): slot s (0..43) of the GP pair-sum (verified) ----
// extended: slots 44..51 = left-linear slot for blade j=S-44 (product = x[b,n,j], weight = w_left)
// slot 52 = zero pad.
constexpr int SCNT[44] = {1,1,1,1,1,1,1,1, 3,1,1,1, 2,2,2,2,2,2, 1,1,1, 3,
                          3, 2,2,2, 1,1,1,1,1,1, 2,2,2, 3, 1,1,1,1,1,1,1,1};
constexpr int T1I[44] = {0,0,0,0,0,0,0,0, 1,1,2,3, 2,1,1,1,1,2, 3,2,1, 1,
                         4, 4,4,5, 6,5,4,4,5,6, 5,4,4, 4, 7,7,7,7,7,7,7,7};
constexpr int T1K[44] = {0,1,2,3,4,5,6,7, 1,0,0,0, 4,4,5,2,3,3, 7,7,7, 6,
                         4, 2,1,1, 7,7,7,0,0,0, 6,6,5, 3, 7,6,5,4,3,2,1,0};
constexpr int T1S[44] = {1,1,1,1,1,1,1,1, 1,1,1,1, 0,1,1,1,1,1, 1,0,1, 1,
                         0, 1,0,0, 0,1,0,1,1,1, 0,1,0, 1, 0,0,1,0,1,0,1,1};
constexpr int T2I[44] = {0,0,0,0,0,0,0,0, 2,0,0,0, 3,3,2,2,3,3, 0,0,0, 2,
                         5, 5,6,6, 0,0,0,0,0,0, 6,6,5, 5, 0,0,0,0,0,0,0,0};
constexpr int T2K[44] = {0,0,0,0,0,0,0,0, 2,0,0,0, 5,6,6,1,1,2, 0,0,0, 5,
                         5, 3,3,2, 0,0,0,0,0,0, 5,4,4, 2, 0,0,0,0,0,0,0,0};
constexpr int T2S[44] = {1,1,1,1,1,1,1,1, 1,1,1,1, 0,0,1,0,0,0, 1,1,1, 0,
                         0, 1,1,0, 1,1,1,1,1,1, 1,0,1, 0, 1,1,1,1,1,1,1,1};
constexpr int T3I[44] = {0,0,0,0,0,0,0,0, 3,0,0,0, 0,0,0,0,0,0, 0,0,0, 3,
                         6, 0,0,0, 0,0,0,0,0,0, 0,0,0, 6, 0,0,0,0,0,0,0,0};
constexpr int T3K[44] = {0,0,0,0,0,0,0,0, 3,0,0,0, 0,0,0,0,0,0, 0,0,0, 4,
                         6, 0,0,0, 0,0,0,0,0,0, 0,0,0, 1, 0,0,0,0,0,0,0,0};
constexpr int T3S[44] = {1,1,1,1,1,1,1,1, 1,1,1,1, 1,1,1,1,1,1, 1,1,1, 1,
                         0, 1,1,1, 1,1,1,1,1,1, 1,1,1, 1, 1,1,1,1,1,1,1,1};
constexpr int CP[44] = {
    0, 1,1,1, 2,2,2, 3,
    4, 5,5,5, 6,6,6, 7,7,7, 8,8,8, 9,
    10, 11,11,11, 12,12,12, 13,13,13, 14,14,14, 15,
    16, 17,17,17, 18,18,18, 19};
// slot-PAIRS incl. lf slots: k = 2n + slot. Q = jh*15 + p. Both slots of a pair share blade j.
constexpr int PPS2[30][2] = {
    {0,8},{22,36},{44,52}, {1,9},{12,23},{26,37},{45,52}, {2,10},{13,24},{27,38},{46,52},
    {3,11},{14,25},{28,39},{47,52},
    {4,15},{18,29},{32,40},{48,52}, {5,16},{19,30},{33,41},{49,52}, {6,17},{20,31},{34,42},{50,52},
    {7,21},{35,43},{51,52}};
constexpr int FRS2[30] = {0,0,0, 1,1,1,1, 2,2,2,2, 3,3,3,3,  0,0,0,0, 1,1,1,1, 2,2,2,2, 3,3,3};

typedef __attribute__((ext_vector_type(8))) short bf16x8;
typedef __attribute__((ext_vector_type(4))) float f32x4;
union U4B { uint4 u; bf16x8 h; };

__device__ __forceinline__ float sigmoidf_(float v) {
    return __builtin_amdgcn_rcpf(1.0f + __expf(-v));
}
__device__ __forceinline__ unsigned pk2(float lo, float hi) {
    __hip_bfloat162 h = __float22bfloat162_rn(make_float2(lo, hi));
    return *reinterpret_cast<unsigned*>(&h);
}
__device__ __forceinline__ void unpkrow(uint4 u, float* v) {
    v[0]=__uint_as_float(u.x<<16); v[1]=__uint_as_float(u.x&0xffff0000u);
    v[2]=__uint_as_float(u.y<<16); v[3]=__uint_as_float(u.y&0xffff0000u);
    v[4]=__uint_as_float(u.z<<16); v[5]=__uint_as_float(u.z&0xffff0000u);
    v[6]=__uint_as_float(u.w<<16); v[7]=__uint_as_float(u.w&0xffff0000u);
}

// tz for slot S (compile-time): S<44 = GP pair-sum; 44..51 = lf (product is x itself); 52 = zero
template<int S>
__device__ __forceinline__ float tz_slot(const float* xf, const float* xr) {
    if constexpr (S >= 52) {
        return 0.0f;
    } else if constexpr (S >= 44) {
        return xf[S - 44];
    } else {
        float v = xf[T1I[S]] * xr[T1K[S]];
        if constexpr (!T1S[S]) v = -v;
        if constexpr (SCNT[S] > 1) {
            if constexpr (T2S[S]) v = fmaf( xf[T2I[S]], xr[T2K[S]], v);
            else                  v = fmaf(-xf[T2I[S]], xr[T2K[S]], v);
        }
        if constexpr (SCNT[S] > 2) {
            if constexpr (T3S[S]) v = fmaf( xf[T3I[S]], xr[T3K[S]], v);
            else                  v = fmaf(-xf[T3I[S]], xr[T3K[S]], v);
        }
        return v;
    }
}

// half-MFMA pass: HALF=0 fills A dwords x,y (n=4lh+0,1), HALF=1 fills z,w (n=4lh+2,3).
// Zero dwords contribute exactly 0 to the K-sum; cf accumulates across both passes.
template<int JH, int P, int HALF>
__device__ __forceinline__ void gp_half(const float (&xf)[2][8], const float (&xrf)[2][8],
                                        const uint4* __restrict__ wsg, int lane,
                                        f32x4 (&cf)[4]) {
    if constexpr (P < 15) {
        constexpr int Q  = JH*15 + P;
        constexpr int S0 = PPS2[Q][0], S1 = PPS2[Q][1], F = FRS2[Q];
        const unsigned d0 = pk2(tz_slot<S0>(xf[0], xrf[0]), tz_slot<S1>(xf[0], xrf[0]));
        const unsigned d1 = pk2(tz_slot<S0>(xf[1], xrf[1]), tz_slot<S1>(xf[1], xrf[1]));
        U4B a;
        if constexpr (HALF == 0) { a.u = make_uint4(d0, d1, 0u, 0u); }
        else                     { a.u = make_uint4(0u, 0u, d0, d1); }
        U4B wb; wb.u = wsg[Q*64 + lane];
        cf[F] = __builtin_amdgcn_mfma_f32_16x16x32_bf16(a.h, wb.h, cf[F], 0, 0, 0);
        gp_half<JH, P+1, HALF>(xf, xrf, wsg, lane, cf);
    }
}

// ---- prep: pack w_up (A-frags under pi), w_down (K=32 B-frags), w_gp+w_left (C B-frags),
//            w_right (A-frags for the xr-GEMM) ----
// sigma (verified): lane l -> row/col = l&15, k-slots ks0 = 8*(l>>4)+2*jp (+1)
// pi(mt,lh,r) = 32*(mt>>1) + 4*(mt&1) + 8*lh + r   (m2 relabeling; see kernel phase D)
__global__ void prep_pack(const float* __restrict__ w_up,
                          const float* __restrict__ w_down,
                          const float* __restrict__ w_gp,
                          const float* __restrict__ w_left,
                          const float* __restrict__ w_right,
                          unsigned* __restrict__ wsu,
                          unsigned* __restrict__ wsd,
                          uint4* __restrict__ wsg,
                          uint4* __restrict__ wsr)
{
    const int t = blockIdx.x * 256 + threadIdx.x;       // 0..14847
    if (t < 8192) {
        // wsu: up A-frags. frag f = mt*8 + i. lane row rho = l&15 -> m2 = pi(mt, rho>>2, rho&3)
        const int d  = t;
        const int f  = d >> 8;
        const int rj = d & 255;
        const int l  = rj >> 2, jp = rj & 3;
        const int mt = f >> 3, i = f & 7;
        const int g  = (i == 0) ? 0 : (i <= 3 ? 1 : (i <= 6 ? 2 : 3));
        const int rho = l & 15;
        const int m2 = 32*(mt>>1) + 4*(mt&1) + 8*(rho>>2) + (rho&3);
        const int n0 = ((l >> 4) << 3) + (jp << 1);
        const float v0 = (n0     < 16) ? w_up[(m2*16 + n0    )*4 + g] : 0.f;
        const float v1 = (n0 + 1 < 16) ? w_up[(m2*16 + n0 + 1)*4 + g] : 0.f;
        wsu[d] = pk2(v0, v1);
    } else if (t < 12288) {
        // wsd: down B-frags, K=32. frag f = kt*8 + i. col m = l&15, k = m2 = 32kt + ks
        const int d  = t - 8192;
        const int f  = d >> 8;
        const int rj = d & 255;
        const int l  = rj >> 2, jp = rj & 3;
        const int kt = f >> 3, i = f & 7;
        const int g  = (i == 0) ? 0 : (i <= 3 ? 1 : (i <= 6 ? 2 : 3));
        const int m  = l & 15;
        const int k0 = 32*kt + ((l >> 4) << 3) + (jp << 1);
        wsd[d] = pk2(w_down[(m*64 + k0    )*4 + g],
                     w_down[(m*64 + k0 + 1)*4 + g]);
    } else if (t < 14208) {
        const int u = t - 12288;                        // 0..1919
        const int l = u & 63, q = u >> 6;               // q 0..29
        const int m = l & 15, lh = l >> 4;
        const int s0 = PPS2[q][0], s1 = PPS2[q][1];
        auto wslot = [&](int S, int n) -> float {
            if (S >= 52) return 0.f;
            if (S >= 44) {
                const int j = S - 44;
                const int gg = (j == 0) ? 0 : (j <= 3 ? 1 : (j <= 6 ? 2 : 3));
                return w_left[(m*16 + n)*4 + gg];
            }
            return w_gp[(m*16 + n)*20 + CP[S]];
        };
        uint4 val;
        { const int n = 4*lh + 0; val.x = pk2(wslot(s0, n), wslot(s1, n)); }
        { const int n = 4*lh + 1; val.y = pk2(wslot(s0, n), wslot(s1, n)); }
        { const int n = 4*lh + 2; val.z = pk2(wslot(s0, n), wslot(s1, n)); }
        { const int n = 4*lh + 3; val.w = pk2(wslot(s0, n), wslot(s1, n)); }
        wsg[q*64 + l] = val;
    } else if (t < 14720) {
        // wsr: xr-GEMM A-frags, one per blade j. row nch = l&15 (output channel),
        // k = input channel (k>=16 -> 0). A[nch][k] = w_right[nch][k][g(j)].
        const int u2 = t - 14208;                       // 0..511
        const int l = u2 & 63, j = u2 >> 6;             // j 0..7
        const int g  = (j == 0) ? 0 : (j <= 3 ? 1 : (j <= 6 ? 2 : 3));
        const int nch = l & 15;
        const int lh2 = l >> 4;
        uint4 val = make_uint4(0u,0u,0u,0u);
        if (lh2 < 2) {
            const int kb = 8*lh2;
            val.x = pk2(w_right[(nch*16+kb+0)*4+g], w_right[(nch*16+kb+1)*4+g]);
            val.y = pk2(w_right[(nch*16+kb+2)*4+g], w_right[(nch*16+kb+3)*4+g]);
            val.z = pk2(w_right[(nch*16+kb+4)*4+g], w_right[(nch*16+kb+5)*4+g]);
            val.w = pk2(w_right[(nch*16+kb+6)*4+g], w_right[(nch*16+kb+7)*4+g]);
        }
        wsr[j*64 + l] = val;
    }
}

__global__ __launch_bounds__(TPB, 4)
void mv_block_kernel(const float* __restrict__ xg,
                     const float* __restrict__ a_norm,
                     const float* __restrict__ b_left,
                     const float* __restrict__ b_up,
                     const float* __restrict__ a_act,
                     const float* __restrict__ b_act,
                     const float* __restrict__ b_down,
                     const uint4* __restrict__ wsu,
                     const uint4* __restrict__ wsd,
                     const uint4* __restrict__ wsg,
                     const uint4* __restrict__ wsr,
                     float* __restrict__ outg)
{
    extern __shared__ float sm[];
    uint4* uXR = ((uint4*)sm) + XRU4;
    const int t = threadIdx.x;
    const int b = t & 63;                                   // lane
    const int w = __builtin_amdgcn_readfirstlane(t >> 6);   // wave 0..3 (uniform)
    const int g = blockIdx.x;
    const int Mtb  = (w & 1) << 4;                          // M-tile base (16 of 32 batch rows)
    const int jh   = w >> 1;                                // blade-half 0/1
    const int lcol = b & 15;
    const int lh   = b >> 4;

    // ---------- stage x (coalesced, f32): 32 batch rows ----------
    {
        const float4* xs = (const float4*)xg + (size_t)g * 1024;
        #pragma unroll
        for (int r = 0; r < 4; ++r) {
            const int idx = r * TPB + t;
            const float4 v = xs[idx];
            const int el = idx >> 5, off = idx & 31;
            *(float4*)&sm[OFF_X + el * XS + off * 4] = v;
        }
    }
    __syncthreads();

    // ---------- phase A' (MFMA right-linear) + in-reg gated normalization -> uXR bf16 ----------
    // swapped GEMM per blade j (own half): xr[nch, b] = wsr(A)[nch,k] x Bf(x)[k,b].
    // C layout: col = lcol = b-local, row = 4lh + r = nch. Norm grades never cross blade-quad.
    {
        uint4 Bf[4];
        #pragma unroll
        for (int q = 0; q < 4; ++q) Bf[q] = make_uint4(0u,0u,0u,0u);
        if (lh < 2) {                    // k-slots >=16 multiply zero A rows
            float4 xk[8];
            const float* xb = &sm[OFF_X + (Mtb + lcol)*XS + (jh<<2)];
            #pragma unroll
            for (int kk = 0; kk < 8; ++kk)
                xk[kk] = *(const float4*)&xb[(8*lh + kk)*8];
            Bf[0] = make_uint4(pk2(xk[0].x,xk[1].x), pk2(xk[2].x,xk[3].x),
                               pk2(xk[4].x,xk[5].x), pk2(xk[6].x,xk[7].x));
            Bf[1] = make_uint4(pk2(xk[0].y,xk[1].y), pk2(xk[2].y,xk[3].y),
                               pk2(xk[4].y,xk[5].y), pk2(xk[6].y,xk[7].y));
            Bf[2] = make_uint4(pk2(xk[0].z,xk[1].z), pk2(xk[2].z,xk[3].z),
                               pk2(xk[4].z,xk[5].z), pk2(xk[6].z,xk[7].z));
            Bf[3] = make_uint4(pk2(xk[0].w,xk[1].w), pk2(xk[2].w,xk[3].w),
                               pk2(xk[4].w,xk[5].w), pk2(xk[6].w,xk[7].w));
        }
        f32x4 ur[4];
        #pragma unroll
        for (int q = 0; q < 4; ++q) {
            U4B a;  a.u  = wsr[((jh<<2) + q)*64 + b];
            U4B bb; bb.u = Bf[q];
            f32x4 z; z[0]=0.f; z[1]=0.f; z[2]=0.f; z[3]=0.f;
            ur[q] = __builtin_amdgcn_mfma_f32_16x16x32_bf16(a.h, bb.h, z, 0, 0, 0);
        }
        unsigned* uw = (unsigned*)(sm + OFF_XR);
        #pragma unroll
        for (int r = 0; r < 4; ++r) {
            const int nch = 4*lh + r;
            const float4 an = *(const float4*)&a_norm[nch*4];
            float v0 = ur[0][r], v1 = ur[1][r], v2 = ur[2][r], v3 = ur[3][r];
            if (jh == 0) {                       // blades 0..3: grade0 + grade1
                const float i0 = __builtin_amdgcn_rcpf(
                    sigmoidf_(an.x)*(sqrtf(v0*v0)-1.0f)+1.0f + 1e-6f);
                const float i1 = __builtin_amdgcn_rcpf(
                    sigmoidf_(an.y)*(sqrtf(v1*v1+v2*v2+v3*v3)-1.0f)+1.0f + 1e-6f);
                v0*=i0; v1*=i1; v2*=i1; v3*=i1;
            } else {                             // blades 4..7: grade2 + grade3
                const float i2 = __builtin_amdgcn_rcpf(
                    sigmoidf_(an.z)*(sqrtf(v0*v0+v1*v1+v2*v2)-1.0f)+1.0f + 1e-6f);
                const float i3 = __builtin_amdgcn_rcpf(
                    sigmoidf_(an.w)*(sqrtf(v3*v3)-1.0f)+1.0f + 1e-6f);
                v0*=i2; v1*=i2; v2*=i2; v3*=i3;
            }
            // uXR[b][nch] uint4 = blades 0..7 bf16; this wave writes its half's 2 dwords
            const int dwb = (((Mtb + lcol)*17 + nch) << 2) + (jh << 1);
            uw[dwb]     = pk2(v0, v1);
            uw[dwb + 1] = pk2(v2, v3);
        }
    }
    __syncthreads();

    // ---------- phase C (MFMA): b_left + lf + gp accumulated together; att = cf/sqrt2 ----------
    // 2 half-passes (n=4lh+{0,1} then {2,3}), 15 pairs each incl. lf slots; cf[0] seeded b_left.
    {
        const int brow = Mtb + lcol;
        f32x4 cf[4];
        {
            const float bl = (jh == 0) ? b_left[lcol] : 0.0f;
            cf[0][0]=bl; cf[0][1]=bl; cf[0][2]=bl; cf[0][3]=bl;
            #pragma unroll
            for (int q = 1; q < 4; ++q) { cf[q][0]=0.f; cf[q][1]=0.f; cf[q][2]=0.f; cf[q][3]=0.f; }
        }
        float xf[2][8], xrf[2][8];
        // half 0: n = 4lh+0, 4lh+1
        #pragma unroll
        for (int jp = 0; jp < 2; ++jp) {
            const int n = 4*lh + jp;
            const float4 u0 = *(const float4*)&sm[OFF_X + brow*XS + n*8];
            const float4 u1 = *(const float4*)&sm[OFF_X + brow*XS + n*8 + 4];
            xf[jp][0]=u0.x; xf[jp][1]=u0.y; xf[jp][2]=u0.z; xf[jp][3]=u0.w;
            xf[jp][4]=u1.x; xf[jp][5]=u1.y; xf[jp][6]=u1.z; xf[jp][7]=u1.w;
            unpkrow(uXR[brow*17 + n], xrf[jp]);
        }
        if (jh == 0) gp_half<0,0,0>(xf, xrf, wsg, b, cf);
        else         gp_half<1,0,0>(xf, xrf, wsg, b, cf);
        // half 1: n = 4lh+2, 4lh+3 (reuse xf/xrf storage)
        #pragma unroll
        for (int jp = 0; jp < 2; ++jp) {
            const int n = 4*lh + 2 + jp;
            const float4 u0 = *(const float4*)&sm[OFF_X + brow*XS + n*8];
            const float4 u1 = *(const float4*)&sm[OFF_X + brow*XS + n*8 + 4];
            xf[jp][0]=u0.x; xf[jp][1]=u0.y; xf[jp][2]=u0.z; xf[jp][3]=u0.w;
            xf[jp][4]=u1.x; xf[jp][5]=u1.y; xf[jp][6]=u1.z; xf[jp][7]=u1.w;
            unpkrow(uXR[brow*17 + n], xrf[jp]);
        }
        if (jh == 0) gp_half<0,0,1>(xf, xrf, wsg, b, cf);
        else         gp_half<1,0,1>(xf, xrf, wsg, b, cf);
        __syncthreads();   // all waves done reading x (X) and xr (uXR)
        // att = cf * inv_sqrt2 -> X region f32 [b][m*8 + j]  (x is dead)
        const float s2 = 0.70710678118654752f;
        #pragma unroll
        for (int r = 0; r < 4; ++r) {
            *(float4*)&sm[OFF_X + (Mtb + 4*lh + r)*XS + (lcol<<3) + (jh<<2)] =
                make_float4(cf[0][r]*s2, cf[1][r]*s2, cf[2][r]*s2, cf[3][r]*s2);
        }
    }
    __syncthreads();

    // ---------- attW bf16 assembly from X (transient regs only) ----------
    // thread covers (np = channel pair, batch): np = 2w | (b>>5), batch = b&31
    {
        const int np = (w << 1) | (b >> 5);
        const int bt = b & 31;
        const float* gx = &sm[OFF_X + bt*XS];
        const float4 a0 = *(const float4*)&gx[np*16];
        const float4 a1 = *(const float4*)&gx[np*16 + 4];
        const float4 b0 = *(const float4*)&gx[np*16 + 8];
        const float4 b1 = *(const float4*)&gx[np*16 + 12];
        unsigned* attW = (unsigned*)(sm + OFF_XR);
        const int bsw = bt ^ ((np >> 2) << 4);
        attW[(0<<8) + (np<<5) + bsw] = pk2(a0.x, b0.x);
        attW[(1<<8) + (np<<5) + bsw] = pk2(a0.y, b0.y);
        attW[(2<<8) + (np<<5) + bsw] = pk2(a0.z, b0.z);
        attW[(3<<8) + (np<<5) + bsw] = pk2(a0.w, b0.w);
        attW[(4<<8) + (np<<5) + bsw] = pk2(a1.x, b1.x);
        attW[(5<<8) + (np<<5) + bsw] = pk2(a1.y, b1.y);
        attW[(6<<8) + (np<<5) + bsw] = pk2(a1.z, b1.z);
        attW[(7<<8) + (np<<5) + bsw] = pk2(a1.w, b1.w);
    }
    __syncthreads();

    // ---------- phase D: swapped up-GEMM (h^T in regs) -> in-reg silu -> reg-packed down-GEMM ----
    // up (per blade i): C'[m2,b] = wsu(A)[m2,n] x attB(B)[n,b]; pi relabel aligns C' rows with
    // down A k-slots. Incremental pack: mte=0 result packed to 8 dwords before mte=1 runs.
    // X region is untouched during D (att f32 parks there).
    f32x4 dC[4];
    #pragma unroll
    for (int q = 0; q < 4; ++q) { dC[q][0]=0.f; dC[q][1]=0.f; dC[q][2]=0.f; dC[q][3]=0.f; }
    {
        // B-frags (att) per blade, loaded once; k>=16 rows multiply zero A -> zeros fine
        uint4 attB[4];
        {
            const unsigned* aw = (const unsigned*)(sm + OFF_XR);
            #pragma unroll
            for (int q = 0; q < 4; ++q) {
                uint4 v = make_uint4(0u,0u,0u,0u);
                if (lh < 2) {
                    const int base = ((jh*4 + q) << 8);
                    const int bb = (Mtb + lcol) ^ (lh << 4);
                    v.x = aw[base + ((4*lh+0)<<5) + bb];
                    v.y = aw[base + ((4*lh+1)<<5) + bb];
                    v.z = aw[base + ((4*lh+2)<<5) + bb];
                    v.w = aw[base + ((4*lh+3)<<5) + bb];
                }
                attB[q] = v;
            }
        }
        #pragma unroll
        for (int kt = 0; kt < 2; ++kt) {
            unsigned pkl[4][2];                     // packed mte=0 A-dwords (8 regs)
            #pragma unroll
            for (int mte = 0; mte < 2; ++mte) {
                const int mt = 2*kt + mte;
                f32x4 uc[4];
                #pragma unroll
                for (int q = 0; q < 4; ++q) {
                    U4B a;  a.u  = wsu[((mt<<3) + jh*4 + q)*64 + b];
                    U4B bb; bb.u = attB[q];
                    f32x4 z; z[0]=0.f; z[1]=0.f; z[2]=0.f; z[3]=0.f;
                    uc[q] = __builtin_amdgcn_mfma_f32_16x16x32_bf16(a.h, bb.h, z, 0, 0, 0);
                }
                // silu in C'-layout: lane holds (b=lcol-col, m2 = m2base + r)
                const int m2base = 32*kt + 4*mte + 8*lh;
                const float4 bup4 = *(const float4*)&b_up[m2base];
                const float* bupp = &bup4.x;
                #pragma unroll
                for (int r = 0; r < 4; ++r) {
                    const float4 aa = *(const float4*)&a_act[(m2base + r)*4];
                    const float4 bc = *(const float4*)&b_act[(m2base + r)*4];
                    float h0 = uc[0][r], h1 = uc[1][r], h2 = uc[2][r], h3 = uc[3][r];
                    if (jh == 0) {                   // blades 0..3: grade0 + grade1
                        h0 += bupp[r];
                        const float g0 = sigmoidf_(fmaf(aa.x, h0, bc.x));
                        const float g1 = sigmoidf_(fmaf(aa.y, h1*h1 + h2*h2 + h3*h3, bc.y));
                        h0 *= g0; h1 *= g1; h2 *= g1; h3 *= g1;
                    } else {                         // blades 4..7: grade2 + grade3
                        const float g2 = sigmoidf_(fmaf(aa.z, h0*h0 + h1*h1 + h2*h2, bc.z));
                        const float g3 = sigmoidf_(fmaf(aa.w, h3*h3, bc.w));
                        h0 *= g2; h1 *= g2; h2 *= g2; h3 *= g3;
                    }
                    uc[0][r]=h0; uc[1][r]=h1; uc[2][r]=h2; uc[3][r]=h3;
                }
                if (mte == 0) {
                    #pragma unroll
                    for (int q = 0; q < 4; ++q) {
                        pkl[q][0] = pk2(uc[q][0], uc[q][1]);
                        pkl[q][1] = pk2(uc[q][2], uc[q][3]);
                    }
                } else {
                    // combine with mte=0 halves and run the down MFMA (K=32 full)
                    #pragma unroll
                    for (int q = 0; q < 4; ++q) {
                        U4B a;
                        a.u.x = pkl[q][0];
                        a.u.y = pkl[q][1];
                        a.u.z = pk2(uc[q][0], uc[q][1]);
                        a.u.w = pk2(uc[q][2], uc[q][3]);
                        U4B wb; wb.u = wsd[((kt<<3) + jh*4 + q)*64 + b];
                        dC[q] = __builtin_amdgcn_mfma_f32_16x16x32_bf16(a.h, wb.h, dC[q], 0, 0, 0);
                    }
                }
            }
        }
    }
    // --- out = att + dC (+ b_down on scalar blade), stored DIRECTLY to global from regs.
    //     att read from X (same addresses this thread wrote in phase C -> same-thread LDS
    //     order guarantees visibility, no barrier). No final barrier / epilogue needed.
    //     Global float4 index: row br (stride 32 float4), dword block (lcol<<1)+jh.
    {
        const float bd = (jh == 0) ? b_down[lcol] : 0.0f;
        float4* og = (float4*)outg + (size_t)g * 1024;
        #pragma unroll
        for (int r = 0; r < 4; ++r) {
            const int br = Mtb + (lh<<2) + r;
            float4 av = *(const float4*)&sm[OFF_X + br*XS + (lcol<<3) + (jh<<2)];
            av.x = (av.x + dC[0][r]) + bd;
            av.y += dC[1][r];
            av.z += dC[2][r];
            av.w += dC[3][r];
            og[br*32 + (lcol<<1) + jh] = av;
        }
    }
}

extern "C" void kernel_launch(void* const* d_in, const int* in_sizes, int n_in,
                              void* d_out, int out_size, void* d_ws, size_t ws_size,
                              hipStream_t stream) {
    const float* x       = (const float*)d_in[0];
    const float* w_right = (const float*)d_in[1];
    const float* a_norm  = (const float*)d_in[2];
    const float* w_gp    = (const float*)d_in[3];
    const float* w_left  = (const float*)d_in[4];
    const float* b_left  = (const float*)d_in[5];
    const float* w_up    = (const float*)d_in[6];
    const float* b_up    = (const float*)d_in[7];
    const float* a_act   = (const float*)d_in[8];
    const float* b_act   = (const float*)d_in[9];
    const float* w_down  = (const float*)d_in[10];
    const float* b_down  = (const float*)d_in[11];
    float* out = (float*)d_out;

    const int B = in_sizes[0] / 128;        // 65536
    const int nblocks = B / 32;             // 2048 (32 batch rows per 256-thread block)

    unsigned* wsu = (unsigned*)d_ws;        // 32 KB up A-frags (pi-ordered)
    unsigned* wsd = wsu + 8192;             // 16 KB down B-frags (K=32)
    uint4*    wsg = (uint4*)(wsd + 4096);   // 30 KB C-phase B-frags (30 slot-pairs x 64 lanes)
    uint4*    wsr = wsg + 1920;             // 8 KB xr-GEMM A-frags (8 blades x 64 lanes)

    prep_pack<<<58, 256, 0, stream>>>(w_up, w_down, w_gp, w_left, w_right,
                                      wsu, wsd, wsg, wsr);

    (void)hipFuncSetAttribute((const void*)mv_block_kernel,
                              hipFuncAttributeMaxDynamicSharedMemorySize, SMEM_BYTES);
    mv_block_kernel<<<nblocks, TPB, SMEM_BYTES, stream>>>(
        x, a_norm, b_left, b_up, a_act, b_act, b_down,
        (const uint4*)wsu, (const uint4*)wsd, (const uint4*)wsg, (const uint4*)wsr, out);
}